// Round 6
// baseline (89.970 us; speedup 1.0000x reference)
//
#include <hip/hip_runtime.h>
#include <hip/hip_cooperative_groups.h>

namespace cg = cooperative_groups;

// ---------------- ws float offsets ----------------
enum : int {
  WS_H1 = 0,      // 64x128  composed node->f1 weight
  WS_H2 = 8192,   // 2x128   composed pos->f1 weight
  WS_H3 = 8448,   // 32x128  per-batch bias into f1 layer
  WS_END = 12544
};

// One cooperative kernel: phase A (prep: H1/H2 column chains + per-batch H3),
// grid.sync(), phase B (per-node fused MLP).
__global__ __launch_bounds__(256) void k_fused(
    const float* __restrict__ h, const float* __restrict__ pos,
    const float* __restrict__ se_w, const float* __restrict__ se_b,
    const float* __restrict__ s1_w, const float* __restrict__ s1_b,
    const float* __restrict__ s2_w, const float* __restrict__ s2_b,
    const float* __restrict__ n1_w, const float* __restrict__ n1_b,
    const float* __restrict__ n2_w, const float* __restrict__ n2_b,
    const float* __restrict__ e1_w, const float* __restrict__ e1_b,
    const float* __restrict__ e2_w, const float* __restrict__ e2_b,
    const float* __restrict__ f1_w, const float* __restrict__ f1_b,
    const float* __restrict__ f2_w, const float* __restrict__ f2_b,
    float* __restrict__ ws, float* __restrict__ out)
{
  __shared__ __align__(16) float smem[11744];
  int blk = blockIdx.x, t = threadIdx.x;

  // =============== Phase A: prep ===============
  if (blk < 16) {
    // ---- H1/H2 column chain, 8 columns per block ----
    // H1[:,c] = 4*S1r@s2_w@n1_w@n2_w@E1r@e2_w@f1_w[:,c] ; H2[:,c] = -4*se_w@(S1e@v5)
    float* VA = smem;          // [<=128][9]
    float* VB = smem + 1152;   // [128][9]
    const int c0 = blk * 8;
    const int j = t & 7, rb = t >> 3;   // rb 0..31
    for (int i = t; i < 512; i += 256) {        // V0 = f1_w[:,c0..c0+7]  (64x8)
      int k = i >> 3, jj = i & 7;
      VA[k * 9 + jj] = f1_w[k * 128 + c0 + jj];
    }
    __syncthreads();
    // S1: VB(128) = e2_w @ VA(64)
    { float a0=0.f,a1=0.f,a2=0.f,a3=0.f;
      #pragma unroll 16
      for (int k = 0; k < 64; ++k) {
        float v = VA[k*9 + j];
        a0 = fmaf(e2_w[rb*64 + k],      v, a0);
        a1 = fmaf(e2_w[(rb+32)*64 + k], v, a1);
        a2 = fmaf(e2_w[(rb+64)*64 + k], v, a2);
        a3 = fmaf(e2_w[(rb+96)*64 + k], v, a3);
      }
      VB[rb*9+j]=a0; VB[(rb+32)*9+j]=a1; VB[(rb+64)*9+j]=a2; VB[(rb+96)*9+j]=a3; }
    __syncthreads();
    // S2: VA(64) = E1r @ VB(128)
    { float a0=0.f,a1=0.f;
      #pragma unroll 16
      for (int k = 0; k < 128; ++k) {
        float v = VB[k*9 + j];
        a0 = fmaf(e1_w[rb*128 + k],      v, a0);
        a1 = fmaf(e1_w[(rb+32)*128 + k], v, a1);
      }
      VA[rb*9+j]=a0; VA[(rb+32)*9+j]=a1; }
    __syncthreads();
    // S3: VB(128) = n2_w @ VA(64)
    { float a0=0.f,a1=0.f,a2=0.f,a3=0.f;
      #pragma unroll 16
      for (int k = 0; k < 64; ++k) {
        float v = VA[k*9 + j];
        a0 = fmaf(n2_w[rb*64 + k],      v, a0);
        a1 = fmaf(n2_w[(rb+32)*64 + k], v, a1);
        a2 = fmaf(n2_w[(rb+64)*64 + k], v, a2);
        a3 = fmaf(n2_w[(rb+96)*64 + k], v, a3);
      }
      VB[rb*9+j]=a0; VB[(rb+32)*9+j]=a1; VB[(rb+64)*9+j]=a2; VB[(rb+96)*9+j]=a3; }
    __syncthreads();
    // S4: VA(64) = n1_w @ VB(128)
    { float a0=0.f,a1=0.f;
      #pragma unroll 16
      for (int k = 0; k < 128; ++k) {
        float v = VB[k*9 + j];
        a0 = fmaf(n1_w[rb*128 + k],      v, a0);
        a1 = fmaf(n1_w[(rb+32)*128 + k], v, a1);
      }
      VA[rb*9+j]=a0; VA[(rb+32)*9+j]=a1; }
    __syncthreads();
    // S5: VB(128) = s2_w @ VA(64)
    { float a0=0.f,a1=0.f,a2=0.f,a3=0.f;
      #pragma unroll 16
      for (int k = 0; k < 64; ++k) {
        float v = VA[k*9 + j];
        a0 = fmaf(s2_w[rb*64 + k],      v, a0);
        a1 = fmaf(s2_w[(rb+32)*64 + k], v, a1);
        a2 = fmaf(s2_w[(rb+64)*64 + k], v, a2);
        a3 = fmaf(s2_w[(rb+96)*64 + k], v, a3);
      }
      VB[rb*9+j]=a0; VB[(rb+32)*9+j]=a1; VB[(rb+64)*9+j]=a2; VB[(rb+96)*9+j]=a3; }
    __syncthreads();
    // S6: H1 rows = 4*S1r@VB ; z = S1e@VB (into VA)
    { float a0=0.f,a1=0.f,z0=0.f,z1=0.f;
      #pragma unroll 16
      for (int k = 0; k < 128; ++k) {
        float v = VB[k*9 + j];
        a0 = fmaf(s1_w[rb*128 + k],       v, a0);
        a1 = fmaf(s1_w[(rb+32)*128 + k],  v, a1);
        z0 = fmaf(s1_w[(128+rb)*128 + k], v, z0);
        z1 = fmaf(s1_w[(160+rb)*128 + k], v, z1);
      }
      ws[WS_H1 + rb*128 + c0 + j]      = 4.f * a0;
      ws[WS_H1 + (rb+32)*128 + c0 + j] = 4.f * a1;
      VA[rb*9+j]=z0; VA[(rb+32)*9+j]=z1; }
    __syncthreads();
    // S7: H2[r2][c] = -4 * se_w[r2]@z
    if (t < 16) {
      int r2 = t >> 3, jj = t & 7;
      float a = 0.f;
      #pragma unroll 16
      for (int k = 0; k < 64; ++k) a = fmaf(se_w[r2*64 + k], VA[k*9 + jj], a);
      ws[WS_H2 + r2*128 + c0 + jj] = -4.f * a;
    }
  } else if (blk < 48) {
    // ---- per-batch H3 chain (coalesced; verbatim from round-5) ----
    int b = blk - 16;
    float* part = smem;        // 256
    float* sX = smem + 256;    // 64
    float* sP = smem + 320;    // 2
    float* L0 = smem + 384;    // 128
    float* L1 = smem + 512;    // 128
    float* L2 = smem + 640;    // 128
    float* L3 = smem + 768;    // 128
    float* M0 = smem + 896;    // 64
    float* M1 = smem + 960;    // 64
    { int k = t & 63, g = t >> 6; float s = 0.f;
      #pragma unroll 8
      for (int jn = g * 32; jn < g * 32 + 32; ++jn) s += h[(b * 128 + jn) * 64 + k];
      part[t] = s; }
    __syncthreads();
    if (t < 64) sX[t] = (part[t] + part[64 + t]) + (part[128 + t] + part[192 + t]);
    else if (t < 66) { int cc = t - 64; float s = 0.f;
      #pragma unroll 16
      for (int jn = 0; jn < 128; ++jn) s += pos[(b * 128 + jn) * 2 + cc];
      sP[cc] = s; }
    __syncthreads();
    // Phase A: L0=xr=X@S1r, L1=k0=se_b@S1e+s1_b, L2=xs=X@S1s, L3=y=(P@se_w)@S1e
    { int g = t >> 7, o = t & 127;
      if (g == 0) {
        float a = 0.f, kk = 0.f;
        #pragma unroll
        for (int k = 0; k < 64; ++k) {
          a  = fmaf(sX[k],   s1_w[k * 128 + o],         a);
          kk = fmaf(se_b[k], s1_w[(128 + k) * 128 + o], kk);
        }
        L0[o] = a; L1[o] = kk + s1_b[o];
      } else {
        float p0 = sP[0], p1 = sP[1];
        float a = 0.f, yy = 0.f;
        #pragma unroll
        for (int k = 0; k < 64; ++k) {
          a = fmaf(sX[k], s1_w[(64 + k) * 128 + o], a);
          float qk = fmaf(p1, se_w[64 + k], p0 * se_w[k]);
          yy = fmaf(qk, s1_w[(128 + k) * 128 + o], yy);
        }
        L2[o] = a; L3[o] = yy;
      } }
    __syncthreads();
    // Phase B: M0 = v = ((xs+y)/64 + 2k0)@s2_w + 2*s2_b ; M1 = u = 2(xr-y)@s2_w
    if (t < 128) { int g = t >> 6, c = t & 63;
      float a = 0.f;
      if (g == 0) {
        #pragma unroll
        for (int o = 0; o < 128; ++o) {
          float r2 = fmaf(2.f, L1[o], (L2[o] + L3[o]) * (1.f / 64.f));
          a = fmaf(r2, s2_w[o * 64 + c], a);
        }
        M0[c] = a + 2.f * s2_b[c];
      } else {
        #pragma unroll
        for (int o = 0; o < 128; ++o)
          a = fmaf(2.f * (L0[o] - L3[o]), s2_w[o * 64 + c], a);
        M1[c] = a;
      } }
    __syncthreads();
    // Phase C: L0 = v@n1_w + n1_b ; L1 = u@n1_w
    { int g = t >> 7, o = t & 127;
      float a = 0.f;
      if (g == 0) {
        #pragma unroll
        for (int k = 0; k < 64; ++k) a = fmaf(M0[k], n1_w[k * 128 + o], a);
        L0[o] = a + n1_b[o];
      } else {
        #pragma unroll
        for (int k = 0; k < 64; ++k) a = fmaf(M1[k], n1_w[k * 128 + o], a);
        L1[o] = a;
      } }
    __syncthreads();
    // Phase D: M0 = c3 = L0@n2_w + n2_b ; M1 = un = L1@n2_w
    if (t < 128) { int g = t >> 6, c = t & 63;
      float a = 0.f;
      if (g == 0) {
        #pragma unroll
        for (int o = 0; o < 128; ++o) a = fmaf(L0[o], n2_w[o * 64 + c], a);
        M0[c] = a + n2_b[c];
      } else {
        #pragma unroll
        for (int o = 0; o < 128; ++o) a = fmaf(L1[o], n2_w[o * 64 + c], a);
        M1[c] = a;
      } }
    __syncthreads();
    // Phase E: L0 = ce = c3@E1r ; L1 = ne = (un + 128*c3)@E1s
    { int g = t >> 7, o = t & 127;
      float a = 0.f;
      if (g == 0) {
        #pragma unroll
        for (int k = 0; k < 64; ++k) a = fmaf(M0[k], e1_w[k * 128 + o], a);
        L0[o] = a;
      } else {
        #pragma unroll
        for (int k = 0; k < 64; ++k) {
          float nb = fmaf(128.f, M0[k], M1[k]);
          a = fmaf(nb, e1_w[(64 + k) * 128 + o], a);
        }
        L1[o] = a;
      } }
    __syncthreads();
    // Phase F: M0 = g3 = (2*ce + ne/64 + 2*e1_b)@e2_w + 2*e2_b
    if (t < 64) { float a = 0.f;
      #pragma unroll
      for (int o = 0; o < 128; ++o) {
        float gv = fmaf(L1[o], (1.f / 64.f), fmaf(2.f, L0[o], 2.f * e1_b[o]));
        a = fmaf(gv, e2_w[o * 64 + t], a);
      }
      M0[t] = a + 2.f * e2_b[t]; }
    __syncthreads();
    // Phase G: h3 = g3@f1_w + f1_b
    if (t < 128) { float a = 0.f;
      #pragma unroll
      for (int k = 0; k < 64; ++k) a = fmaf(M0[k], f1_w[k * 128 + t], a);
      ws[WS_H3 + b * 128 + t] = a + f1_b[t]; }
  }

  __threadfence();            // device-scope release of ws writes (cross-XCD)
  cg::this_grid().sync();
  __threadfence();            // acquire side

  // =============== Phase B: per-node fused MLP ===============
  float* lH1  = smem;          // [64][128]
  float* lH2  = smem + 8192;   // [2][128]
  float* lh3  = smem + 8448;   // [128]
  float* lf2b = smem + 8576;   // [64]
  float* lx   = smem + 8640;   // [16][64]
  float* lp   = smem + 9664;   // [16][2]
  float* lh1  = smem + 9696;   // [16][128]
  int b = blk >> 3, j0 = (blk & 7) * 16;
  for (int i = t; i < 2048; i += 256) ((float4*)lH1)[i] = ((const float4*)(ws + WS_H1))[i];
  if (t < 64) ((float4*)lH2)[t] = ((const float4*)(ws + WS_H2))[t];
  if (t < 128) lh3[t] = ws[WS_H3 + b * 128 + t];
  if (t < 64) lf2b[t] = f2_b[t];
  ((float4*)lx)[t] = ((const float4*)(h + (size_t)(b * 128 + j0) * 64))[t];
  if (t < 32) lp[t] = pos[(b * 128 + j0) * 2 + t];
  __syncthreads();
  // h1 = relu(x@H1 + p@H2 + h3)
  {
    int d = t & 127, g = t >> 7, n0 = g * 8;
    float acc[8];
    #pragma unroll
    for (int i = 0; i < 8; ++i)
      acc[i] = lh3[d] + lp[(n0 + i) * 2] * lH2[d] + lp[(n0 + i) * 2 + 1] * lH2[128 + d];
    #pragma unroll 4
    for (int k = 0; k < 64; k += 4) {
      float h0 = lH1[k * 128 + d], h1v = lH1[(k + 1) * 128 + d],
            h2v = lH1[(k + 2) * 128 + d], h3v = lH1[(k + 3) * 128 + d];
      #pragma unroll
      for (int i = 0; i < 8; ++i) {
        float4 xv = *(const float4*)&lx[(n0 + i) * 64 + k];
        acc[i] = fmaf(xv.x, h0, fmaf(xv.y, h1v, fmaf(xv.z, h2v, fmaf(xv.w, h3v, acc[i]))));
      }
    }
    #pragma unroll
    for (int i = 0; i < 8; ++i) lh1[(n0 + i) * 128 + d] = fmaxf(acc[i], 0.f);
  }
  __syncthreads();
  // out = relu(h1@f2_w + f2_b); f2_w read from global (32 KB, L2-resident)
  {
    int d = t & 63, g = t >> 6, n0 = g * 4;
    float acc[4];
    #pragma unroll
    for (int i = 0; i < 4; ++i) acc[i] = lf2b[d];
    #pragma unroll 4
    for (int k = 0; k < 128; k += 4) {
      float f0 = f2_w[k * 64 + d], f1v = f2_w[(k + 1) * 64 + d],
            f2v = f2_w[(k + 2) * 64 + d], f3v = f2_w[(k + 3) * 64 + d];
      #pragma unroll
      for (int i = 0; i < 4; ++i) {
        float4 hv = *(const float4*)&lh1[(n0 + i) * 128 + k];
        acc[i] = fmaf(hv.x, f0, fmaf(hv.y, f1v, fmaf(hv.z, f2v, fmaf(hv.w, f3v, acc[i]))));
      }
    }
    #pragma unroll
    for (int i = 0; i < 4; ++i)
      out[(size_t)(b * 128 + j0 + n0 + i) * 64 + d] = fmaxf(acc[i], 0.f);
  }
}

extern "C" void kernel_launch(void* const* d_in, const int* in_sizes, int n_in,
                              void* d_out, int out_size, void* d_ws, size_t ws_size,
                              hipStream_t stream) {
  const float* h    = (const float*)d_in[0];
  const float* pos  = (const float*)d_in[1];
  const float* se_w = (const float*)d_in[2];
  const float* se_b = (const float*)d_in[3];
  const float* s1_w = (const float*)d_in[4];
  const float* s1_b = (const float*)d_in[5];
  const float* s2_w = (const float*)d_in[6];
  const float* s2_b = (const float*)d_in[7];
  const float* n1_w = (const float*)d_in[8];
  const float* n1_b = (const float*)d_in[9];
  const float* n2_w = (const float*)d_in[10];
  const float* n2_b = (const float*)d_in[11];
  const float* e1_w = (const float*)d_in[12];
  const float* e1_b = (const float*)d_in[13];
  const float* e2_w = (const float*)d_in[14];
  const float* e2_b = (const float*)d_in[15];
  const float* f1_w = (const float*)d_in[16];
  const float* f1_b = (const float*)d_in[17];
  const float* f2_w = (const float*)d_in[18];
  const float* f2_b = (const float*)d_in[19];
  float* ws = (float*)d_ws;
  float* out = (float*)d_out;

  void* args[] = { (void*)&h, (void*)&pos, (void*)&se_w, (void*)&se_b,
                   (void*)&s1_w, (void*)&s1_b, (void*)&s2_w, (void*)&s2_b,
                   (void*)&n1_w, (void*)&n1_b, (void*)&n2_w, (void*)&n2_b,
                   (void*)&e1_w, (void*)&e1_b, (void*)&e2_w, (void*)&e2_b,
                   (void*)&f1_w, (void*)&f1_b, (void*)&f2_w, (void*)&f2_b,
                   (void*)&ws, (void*)&out };
  hipLaunchCooperativeKernel((const void*)k_fused, dim3(256), dim3(256),
                             args, 0, stream);
}

// Round 7
// 33.113 us; speedup vs baseline: 2.7171x; 2.7171x over previous
//
#include <hip/hip_runtime.h>

// ---------------- ws float offsets ----------------
enum : int {
  WS_H1 = 0,      // 64x128  composed node->f1 weight
  WS_H2 = 8192,   // 2x128   composed pos->f1 weight
  WS_H3 = 8448,   // 32x128  per-batch bias into f1 layer
  WS_END = 12544
};

// ---------------- K1: k_prep (48 blocks x 256) ----------------
// blocks 0..15: H1/H2 columns, 8 per block (coalesced row-block layout)
// blocks 16..47: per-batch H3 chain (batch = blk-16)
__global__ __launch_bounds__(256) void k_prep(
    const float* __restrict__ h, const float* __restrict__ pos,
    const float* __restrict__ se_w, const float* __restrict__ se_b,
    const float* __restrict__ s1_w, const float* __restrict__ s1_b,
    const float* __restrict__ s2_w, const float* __restrict__ s2_b,
    const float* __restrict__ n1_w, const float* __restrict__ n1_b,
    const float* __restrict__ n2_w, const float* __restrict__ n2_b,
    const float* __restrict__ e1_w, const float* __restrict__ e1_b,
    const float* __restrict__ e2_w, const float* __restrict__ e2_b,
    const float* __restrict__ f1_w, const float* __restrict__ f1_b,
    float* __restrict__ ws)
{
  __shared__ __align__(16) float smem[2304];
  int blk = blockIdx.x, t = threadIdx.x;

  if (blk < 16) {
    // ---- H1/H2 column chain, 8 columns per block ----
    // H1[:,c] = 4*S1r@s2_w@n1_w@n2_w@E1r@e2_w@f1_w[:,c] ; H2[:,c] = -4*se_w@(S1e@v5)
    float* VA = smem;          // [<=128][9]
    float* VB = smem + 1152;   // [128][9]
    const int c0 = blk * 8;
    const int j = t & 7, rb = t >> 3;   // rb 0..31
    for (int i = t; i < 512; i += 256) {        // V0 = f1_w[:,c0..c0+7]  (64x8)
      int k = i >> 3, jj = i & 7;
      VA[k * 9 + jj] = f1_w[k * 128 + c0 + jj];
    }
    __syncthreads();
    // S1: VB(128) = e2_w @ VA(64)
    { float a0=0.f,a1=0.f,a2=0.f,a3=0.f;
      #pragma unroll 16
      for (int k = 0; k < 64; ++k) {
        float v = VA[k*9 + j];
        a0 = fmaf(e2_w[rb*64 + k],      v, a0);
        a1 = fmaf(e2_w[(rb+32)*64 + k], v, a1);
        a2 = fmaf(e2_w[(rb+64)*64 + k], v, a2);
        a3 = fmaf(e2_w[(rb+96)*64 + k], v, a3);
      }
      VB[rb*9+j]=a0; VB[(rb+32)*9+j]=a1; VB[(rb+64)*9+j]=a2; VB[(rb+96)*9+j]=a3; }
    __syncthreads();
    // S2: VA(64) = E1r @ VB(128)
    { float a0=0.f,a1=0.f;
      #pragma unroll 16
      for (int k = 0; k < 128; ++k) {
        float v = VB[k*9 + j];
        a0 = fmaf(e1_w[rb*128 + k],      v, a0);
        a1 = fmaf(e1_w[(rb+32)*128 + k], v, a1);
      }
      VA[rb*9+j]=a0; VA[(rb+32)*9+j]=a1; }
    __syncthreads();
    // S3: VB(128) = n2_w @ VA(64)
    { float a0=0.f,a1=0.f,a2=0.f,a3=0.f;
      #pragma unroll 16
      for (int k = 0; k < 64; ++k) {
        float v = VA[k*9 + j];
        a0 = fmaf(n2_w[rb*64 + k],      v, a0);
        a1 = fmaf(n2_w[(rb+32)*64 + k], v, a1);
        a2 = fmaf(n2_w[(rb+64)*64 + k], v, a2);
        a3 = fmaf(n2_w[(rb+96)*64 + k], v, a3);
      }
      VB[rb*9+j]=a0; VB[(rb+32)*9+j]=a1; VB[(rb+64)*9+j]=a2; VB[(rb+96)*9+j]=a3; }
    __syncthreads();
    // S4: VA(64) = n1_w @ VB(128)
    { float a0=0.f,a1=0.f;
      #pragma unroll 16
      for (int k = 0; k < 128; ++k) {
        float v = VB[k*9 + j];
        a0 = fmaf(n1_w[rb*128 + k],      v, a0);
        a1 = fmaf(n1_w[(rb+32)*128 + k], v, a1);
      }
      VA[rb*9+j]=a0; VA[(rb+32)*9+j]=a1; }
    __syncthreads();
    // S5: VB(128) = s2_w @ VA(64)
    { float a0=0.f,a1=0.f,a2=0.f,a3=0.f;
      #pragma unroll 16
      for (int k = 0; k < 64; ++k) {
        float v = VA[k*9 + j];
        a0 = fmaf(s2_w[rb*64 + k],      v, a0);
        a1 = fmaf(s2_w[(rb+32)*64 + k], v, a1);
        a2 = fmaf(s2_w[(rb+64)*64 + k], v, a2);
        a3 = fmaf(s2_w[(rb+96)*64 + k], v, a3);
      }
      VB[rb*9+j]=a0; VB[(rb+32)*9+j]=a1; VB[(rb+64)*9+j]=a2; VB[(rb+96)*9+j]=a3; }
    __syncthreads();
    // S6: H1 rows = 4*S1r@VB ; z = S1e@VB (into VA)
    { float a0=0.f,a1=0.f,z0=0.f,z1=0.f;
      #pragma unroll 16
      for (int k = 0; k < 128; ++k) {
        float v = VB[k*9 + j];
        a0 = fmaf(s1_w[rb*128 + k],       v, a0);
        a1 = fmaf(s1_w[(rb+32)*128 + k],  v, a1);
        z0 = fmaf(s1_w[(128+rb)*128 + k], v, z0);
        z1 = fmaf(s1_w[(160+rb)*128 + k], v, z1);
      }
      ws[WS_H1 + rb*128 + c0 + j]      = 4.f * a0;
      ws[WS_H1 + (rb+32)*128 + c0 + j] = 4.f * a1;
      VA[rb*9+j]=z0; VA[(rb+32)*9+j]=z1; }
    __syncthreads();
    // S7: H2[r2][c] = -4 * se_w[r2]@z
    if (t < 16) {
      int r2 = t >> 3, jj = t & 7;
      float a = 0.f;
      #pragma unroll 16
      for (int k = 0; k < 64; ++k) a = fmaf(se_w[r2*64 + k], VA[k*9 + jj], a);
      ws[WS_H2 + r2*128 + c0 + jj] = -4.f * a;
    }
  } else {
    // ---- per-batch H3 chain ----
    int b = blk - 16;
    float* part = smem;        // 256
    float* sX = smem + 256;    // 64
    float* sP = smem + 320;    // 2
    float* L0 = smem + 384;    // 128
    float* L1 = smem + 512;    // 128
    float* L2 = smem + 640;    // 128
    float* L3 = smem + 768;    // 128
    float* M0 = smem + 896;    // 64
    float* M1 = smem + 960;    // 64
    { int k = t & 63, g = t >> 6; float s = 0.f;
      #pragma unroll 8
      for (int jn = g * 32; jn < g * 32 + 32; ++jn) s += h[(b * 128 + jn) * 64 + k];
      part[t] = s; }
    __syncthreads();
    if (t < 64) sX[t] = (part[t] + part[64 + t]) + (part[128 + t] + part[192 + t]);
    else if (t < 66) { int cc = t - 64; float s = 0.f;
      #pragma unroll 16
      for (int jn = 0; jn < 128; ++jn) s += pos[(b * 128 + jn) * 2 + cc];
      sP[cc] = s; }
    __syncthreads();
    // Phase A: L0=xr=X@S1r, L1=k0=se_b@S1e+s1_b, L2=xs=X@S1s, L3=y=(P@se_w)@S1e
    { int g = t >> 7, o = t & 127;
      if (g == 0) {
        float a = 0.f, kk = 0.f;
        #pragma unroll
        for (int k = 0; k < 64; ++k) {
          a  = fmaf(sX[k],   s1_w[k * 128 + o],         a);
          kk = fmaf(se_b[k], s1_w[(128 + k) * 128 + o], kk);
        }
        L0[o] = a; L1[o] = kk + s1_b[o];
      } else {
        float p0 = sP[0], p1 = sP[1];
        float a = 0.f, yy = 0.f;
        #pragma unroll
        for (int k = 0; k < 64; ++k) {
          a = fmaf(sX[k], s1_w[(64 + k) * 128 + o], a);
          float qk = fmaf(p1, se_w[64 + k], p0 * se_w[k]);
          yy = fmaf(qk, s1_w[(128 + k) * 128 + o], yy);
        }
        L2[o] = a; L3[o] = yy;
      } }
    __syncthreads();
    // Phase B: M0 = v = ((xs+y)/64 + 2k0)@s2_w + 2*s2_b ; M1 = u = 2(xr-y)@s2_w
    if (t < 128) { int g = t >> 6, c = t & 63;
      float a = 0.f;
      if (g == 0) {
        #pragma unroll
        for (int o = 0; o < 128; ++o) {
          float r2 = fmaf(2.f, L1[o], (L2[o] + L3[o]) * (1.f / 64.f));
          a = fmaf(r2, s2_w[o * 64 + c], a);
        }
        M0[c] = a + 2.f * s2_b[c];
      } else {
        #pragma unroll
        for (int o = 0; o < 128; ++o)
          a = fmaf(2.f * (L0[o] - L3[o]), s2_w[o * 64 + c], a);
        M1[c] = a;
      } }
    __syncthreads();
    // Phase C: L0 = v@n1_w + n1_b ; L1 = u@n1_w
    { int g = t >> 7, o = t & 127;
      float a = 0.f;
      if (g == 0) {
        #pragma unroll
        for (int k = 0; k < 64; ++k) a = fmaf(M0[k], n1_w[k * 128 + o], a);
        L0[o] = a + n1_b[o];
      } else {
        #pragma unroll
        for (int k = 0; k < 64; ++k) a = fmaf(M1[k], n1_w[k * 128 + o], a);
        L1[o] = a;
      } }
    __syncthreads();
    // Phase D: M0 = c3 = L0@n2_w + n2_b ; M1 = un = L1@n2_w
    if (t < 128) { int g = t >> 6, c = t & 63;
      float a = 0.f;
      if (g == 0) {
        #pragma unroll
        for (int o = 0; o < 128; ++o) a = fmaf(L0[o], n2_w[o * 64 + c], a);
        M0[c] = a + n2_b[c];
      } else {
        #pragma unroll
        for (int o = 0; o < 128; ++o) a = fmaf(L1[o], n2_w[o * 64 + c], a);
        M1[c] = a;
      } }
    __syncthreads();
    // Phase E: L0 = ce = c3@E1r ; L1 = ne = (un + 128*c3)@E1s
    { int g = t >> 7, o = t & 127;
      float a = 0.f;
      if (g == 0) {
        #pragma unroll
        for (int k = 0; k < 64; ++k) a = fmaf(M0[k], e1_w[k * 128 + o], a);
        L0[o] = a;
      } else {
        #pragma unroll
        for (int k = 0; k < 64; ++k) {
          float nb = fmaf(128.f, M0[k], M1[k]);
          a = fmaf(nb, e1_w[(64 + k) * 128 + o], a);
        }
        L1[o] = a;
      } }
    __syncthreads();
    // Phase F: M0 = g3 = (2*ce + ne/64 + 2*e1_b)@e2_w + 2*e2_b
    if (t < 64) { float a = 0.f;
      #pragma unroll
      for (int o = 0; o < 128; ++o) {
        float gv = fmaf(L1[o], (1.f / 64.f), fmaf(2.f, L0[o], 2.f * e1_b[o]));
        a = fmaf(gv, e2_w[o * 64 + t], a);
      }
      M0[t] = a + 2.f * e2_b[t]; }
    __syncthreads();
    // Phase G: h3 = g3@f1_w + f1_b
    if (t < 128) { float a = 0.f;
      #pragma unroll
      for (int k = 0; k < 64; ++k) a = fmaf(M0[k], f1_w[k * 128 + t], a);
      ws[WS_H3 + b * 128 + t] = a + f1_b[t]; }
  }
}

// ---------------- K2: per-node fused MLP (LDS ~46 KB) ----------------
__global__ __launch_bounds__(256) void k_main(
    const float* __restrict__ h, const float* __restrict__ pos,
    const float* __restrict__ f2_w, const float* __restrict__ f2_b,
    const float* __restrict__ ws, float* __restrict__ out)
{
  __shared__ __align__(16) float lH1[64 * 128];  // [k][d]  32 KB
  __shared__ __align__(16) float lH2[2 * 128];
  __shared__ float lh3[128], lf2b[64];
  __shared__ __align__(16) float lx[16 * 64];    // [n][k]
  __shared__ float lp[16 * 2];
  __shared__ __align__(16) float lh1[16 * 128];  // [n][k]
  int blk = blockIdx.x, t = threadIdx.x;
  int b = blk >> 3, j0 = (blk & 7) * 16;
  for (int i = t; i < 2048; i += 256) ((float4*)lH1)[i] = ((const float4*)(ws + WS_H1))[i];
  if (t < 64) ((float4*)lH2)[t] = ((const float4*)(ws + WS_H2))[t];
  if (t < 128) lh3[t] = ws[WS_H3 + b * 128 + t];
  if (t < 64) lf2b[t] = f2_b[t];
  ((float4*)lx)[t] = ((const float4*)(h + (size_t)(b * 128 + j0) * 64))[t];
  if (t < 32) lp[t] = pos[(b * 128 + j0) * 2 + t];
  __syncthreads();
  // h1 = relu(x@H1 + p@H2 + h3)
  {
    int d = t & 127, g = t >> 7, n0 = g * 8;
    float acc[8];
    #pragma unroll
    for (int i = 0; i < 8; ++i)
      acc[i] = lh3[d] + lp[(n0 + i) * 2] * lH2[d] + lp[(n0 + i) * 2 + 1] * lH2[128 + d];
    #pragma unroll 4
    for (int k = 0; k < 64; k += 4) {
      float h0 = lH1[k * 128 + d], h1v = lH1[(k + 1) * 128 + d],
            h2v = lH1[(k + 2) * 128 + d], h3v = lH1[(k + 3) * 128 + d];
      #pragma unroll
      for (int i = 0; i < 8; ++i) {
        float4 xv = *(const float4*)&lx[(n0 + i) * 64 + k];
        acc[i] = fmaf(xv.x, h0, fmaf(xv.y, h1v, fmaf(xv.z, h2v, fmaf(xv.w, h3v, acc[i]))));
      }
    }
    #pragma unroll
    for (int i = 0; i < 8; ++i) lh1[(n0 + i) * 128 + d] = fmaxf(acc[i], 0.f);
  }
  __syncthreads();
  // out = relu(h1@f2_w + f2_b); f2_w read from global (32 KB, L2-resident)
  {
    int d = t & 63, g = t >> 6, n0 = g * 4;
    float acc[4];
    #pragma unroll
    for (int i = 0; i < 4; ++i) acc[i] = lf2b[d];
    #pragma unroll 4
    for (int k = 0; k < 128; k += 4) {
      float f0 = f2_w[k * 64 + d], f1v = f2_w[(k + 1) * 64 + d],
            f2v = f2_w[(k + 2) * 64 + d], f3v = f2_w[(k + 3) * 64 + d];
      #pragma unroll
      for (int i = 0; i < 4; ++i) {
        float4 hv = *(const float4*)&lh1[(n0 + i) * 128 + k];
        acc[i] = fmaf(hv.x, f0, fmaf(hv.y, f1v, fmaf(hv.z, f2v, fmaf(hv.w, f3v, acc[i]))));
      }
    }
    #pragma unroll
    for (int i = 0; i < 4; ++i)
      out[(size_t)(b * 128 + j0 + n0 + i) * 64 + d] = fmaxf(acc[i], 0.f);
  }
}

extern "C" void kernel_launch(void* const* d_in, const int* in_sizes, int n_in,
                              void* d_out, int out_size, void* d_ws, size_t ws_size,
                              hipStream_t stream) {
  const float* h    = (const float*)d_in[0];
  const float* pos  = (const float*)d_in[1];
  const float* se_w = (const float*)d_in[2];
  const float* se_b = (const float*)d_in[3];
  const float* s1_w = (const float*)d_in[4];
  const float* s1_b = (const float*)d_in[5];
  const float* s2_w = (const float*)d_in[6];
  const float* s2_b = (const float*)d_in[7];
  const float* n1_w = (const float*)d_in[8];
  const float* n1_b = (const float*)d_in[9];
  const float* n2_w = (const float*)d_in[10];
  const float* n2_b = (const float*)d_in[11];
  const float* e1_w = (const float*)d_in[12];
  const float* e1_b = (const float*)d_in[13];
  const float* e2_w = (const float*)d_in[14];
  const float* e2_b = (const float*)d_in[15];
  const float* f1_w = (const float*)d_in[16];
  const float* f1_b = (const float*)d_in[17];
  const float* f2_w = (const float*)d_in[18];
  const float* f2_b = (const float*)d_in[19];
  float* ws = (float*)d_ws;
  float* out = (float*)d_out;

  hipLaunchKernelGGL(k_prep, dim3(48), dim3(256), 0, stream,
                     h, pos, se_w, se_b, s1_w, s1_b, s2_w, s2_b,
                     n1_w, n1_b, n2_w, n2_b, e1_w, e1_b, e2_w, e2_b,
                     f1_w, f1_b, ws);
  hipLaunchKernelGGL(k_main, dim3(256), dim3(256), 0, stream, h, pos, f2_w, f2_b, ws, out);
}

// Round 8
// 27.414 us; speedup vs baseline: 3.2819x; 1.2079x over previous
//
#include <hip/hip_runtime.h>

// ---------------- ws float offsets ----------------
enum : int {
  WS_H1 = 0,      // 64x128  composed node->f1 weight
  WS_H2 = 8192,   // 2x128   composed pos->f1 weight
  WS_H3 = 8448,   // 32x128  per-batch bias into f1 layer
  WS_END = 12544
};

// ---------------- K1: k_prep (64 blocks x 256) ----------------
// blocks 0..31: H1/H2 columns, 4 per block (coalesced row-block layout)
// blocks 32..63: per-batch H3 chain (batch = blk-32)
__global__ __launch_bounds__(256) void k_prep(
    const float* __restrict__ h, const float* __restrict__ pos,
    const float* __restrict__ se_w, const float* __restrict__ se_b,
    const float* __restrict__ s1_w, const float* __restrict__ s1_b,
    const float* __restrict__ s2_w, const float* __restrict__ s2_b,
    const float* __restrict__ n1_w, const float* __restrict__ n1_b,
    const float* __restrict__ n2_w, const float* __restrict__ n2_b,
    const float* __restrict__ e1_w, const float* __restrict__ e1_b,
    const float* __restrict__ e2_w, const float* __restrict__ e2_b,
    const float* __restrict__ f1_w, const float* __restrict__ f1_b,
    float* __restrict__ ws)
{
  __shared__ __align__(16) float smem[1280];
  int blk = blockIdx.x, t = threadIdx.x;

  if (blk < 32) {
    // ---- H1/H2 column chain, 4 columns per block ----
    // H1[:,c] = 4*S1r@s2_w@n1_w@n2_w@E1r@e2_w@f1_w[:,c] ; H2[:,c] = -4*se_w@(S1e@v5)
    float* VA = smem;         // [128][5]
    float* VB = smem + 640;   // [128][5]
    const int c0 = blk * 4;
    const int j = t & 3, rb = t >> 2;   // rb 0..63
    if (t < 256) { int k = t >> 2, jj = t & 3;   // V0 = f1_w[:,c0..c0+3] (64x4)
      VA[k * 5 + jj] = f1_w[k * 128 + c0 + jj];
    }
    __syncthreads();
    // S1: VB(128) = e2_w @ VA(64)
    { float a0 = 0.f, a1 = 0.f;
      #pragma unroll 16
      for (int k = 0; k < 64; ++k) {
        float v = VA[k*5 + j];
        a0 = fmaf(e2_w[rb*64 + k],      v, a0);
        a1 = fmaf(e2_w[(rb+64)*64 + k], v, a1);
      }
      VB[rb*5+j] = a0; VB[(rb+64)*5+j] = a1; }
    __syncthreads();
    // S2: VA(64) = E1r @ VB(128)
    { float a = 0.f;
      #pragma unroll 16
      for (int k = 0; k < 128; ++k) a = fmaf(e1_w[rb*128 + k], VB[k*5 + j], a);
      VA[rb*5+j] = a; }
    __syncthreads();
    // S3: VB(128) = n2_w @ VA(64)
    { float a0 = 0.f, a1 = 0.f;
      #pragma unroll 16
      for (int k = 0; k < 64; ++k) {
        float v = VA[k*5 + j];
        a0 = fmaf(n2_w[rb*64 + k],      v, a0);
        a1 = fmaf(n2_w[(rb+64)*64 + k], v, a1);
      }
      VB[rb*5+j] = a0; VB[(rb+64)*5+j] = a1; }
    __syncthreads();
    // S4: VA(64) = n1_w @ VB(128)
    { float a = 0.f;
      #pragma unroll 16
      for (int k = 0; k < 128; ++k) a = fmaf(n1_w[rb*128 + k], VB[k*5 + j], a);
      VA[rb*5+j] = a; }
    __syncthreads();
    // S5: VB(128) = s2_w @ VA(64)
    { float a0 = 0.f, a1 = 0.f;
      #pragma unroll 16
      for (int k = 0; k < 64; ++k) {
        float v = VA[k*5 + j];
        a0 = fmaf(s2_w[rb*64 + k],      v, a0);
        a1 = fmaf(s2_w[(rb+64)*64 + k], v, a1);
      }
      VB[rb*5+j] = a0; VB[(rb+64)*5+j] = a1; }
    __syncthreads();
    // S6: H1 row rb = 4*S1r[rb]@VB ; z[rb] = S1e[rb]@VB (into VA)
    { float a = 0.f, z = 0.f;
      #pragma unroll 16
      for (int k = 0; k < 128; ++k) {
        float v = VB[k*5 + j];
        a = fmaf(s1_w[rb*128 + k],       v, a);
        z = fmaf(s1_w[(128+rb)*128 + k], v, z);
      }
      ws[WS_H1 + rb*128 + c0 + j] = 4.f * a;
      VA[rb*5+j] = z; }
    __syncthreads();
    // S7: H2[r2][c] = -4 * se_w[r2]@z
    if (t < 8) {
      int r2 = t >> 2, jj = t & 3;
      float a = 0.f;
      #pragma unroll 16
      for (int k = 0; k < 64; ++k) a = fmaf(se_w[r2*64 + k], VA[k*5 + jj], a);
      ws[WS_H2 + r2*128 + c0 + jj] = -4.f * a;
    }
  } else {
    // ---- per-batch H3 chain ----
    int b = blk - 32;
    float* part = smem;        // 256
    float* sX = smem + 256;    // 64
    float* sP = smem + 320;    // 2
    float* L0 = smem + 384;    // 128
    float* L1 = smem + 512;    // 128
    float* L2 = smem + 640;    // 128
    float* L3 = smem + 768;    // 128
    float* M0 = smem + 896;    // 64
    float* M1 = smem + 960;    // 64
    { int k = t & 63, g = t >> 6; float s = 0.f;
      #pragma unroll 8
      for (int jn = g * 32; jn < g * 32 + 32; ++jn) s += h[(b * 128 + jn) * 64 + k];
      part[t] = s; }
    __syncthreads();
    if (t < 64) sX[t] = (part[t] + part[64 + t]) + (part[128 + t] + part[192 + t]);
    else if (t < 128) {
      // pos sums: lane l of wave 1; flat idx b*256 + 64m + l, 4 coalesced loads
      int l = t - 64;
      const float* pb = pos + b * 256;
      float s = (pb[l] + pb[64 + l]) + (pb[128 + l] + pb[192 + l]);
      #pragma unroll
      for (int m = 2; m <= 32; m <<= 1) s += __shfl_xor(s, m, 64);
      if (l < 2) sP[l] = s;
    }
    __syncthreads();
    // Phase A: L0=xr=X@S1r, L1=k0=se_b@S1e+s1_b, L2=xs=X@S1s, L3=y=(P@se_w)@S1e
    { int g = t >> 7, o = t & 127;
      if (g == 0) {
        float a = 0.f, kk = 0.f;
        #pragma unroll
        for (int k = 0; k < 64; ++k) {
          a  = fmaf(sX[k],   s1_w[k * 128 + o],         a);
          kk = fmaf(se_b[k], s1_w[(128 + k) * 128 + o], kk);
        }
        L0[o] = a; L1[o] = kk + s1_b[o];
      } else {
        float p0 = sP[0], p1 = sP[1];
        float a = 0.f, yy = 0.f;
        #pragma unroll
        for (int k = 0; k < 64; ++k) {
          a = fmaf(sX[k], s1_w[(64 + k) * 128 + o], a);
          float qk = fmaf(p1, se_w[64 + k], p0 * se_w[k]);
          yy = fmaf(qk, s1_w[(128 + k) * 128 + o], yy);
        }
        L2[o] = a; L3[o] = yy;
      } }
    __syncthreads();
    // Phase B: M0 = v = ((xs+y)/64 + 2k0)@s2_w + 2*s2_b ; M1 = u = 2(xr-y)@s2_w
    if (t < 128) { int g = t >> 6, c = t & 63;
      float a = 0.f;
      if (g == 0) {
        #pragma unroll
        for (int o = 0; o < 128; ++o) {
          float r2 = fmaf(2.f, L1[o], (L2[o] + L3[o]) * (1.f / 64.f));
          a = fmaf(r2, s2_w[o * 64 + c], a);
        }
        M0[c] = a + 2.f * s2_b[c];
      } else {
        #pragma unroll
        for (int o = 0; o < 128; ++o)
          a = fmaf(2.f * (L0[o] - L3[o]), s2_w[o * 64 + c], a);
        M1[c] = a;
      } }
    __syncthreads();
    // Phase C: L0 = v@n1_w + n1_b ; L1 = u@n1_w
    { int g = t >> 7, o = t & 127;
      float a = 0.f;
      if (g == 0) {
        #pragma unroll
        for (int k = 0; k < 64; ++k) a = fmaf(M0[k], n1_w[k * 128 + o], a);
        L0[o] = a + n1_b[o];
      } else {
        #pragma unroll
        for (int k = 0; k < 64; ++k) a = fmaf(M1[k], n1_w[k * 128 + o], a);
        L1[o] = a;
      } }
    __syncthreads();
    // Phase D: M0 = c3 = L0@n2_w + n2_b ; M1 = un = L1@n2_w
    if (t < 128) { int g = t >> 6, c = t & 63;
      float a = 0.f;
      if (g == 0) {
        #pragma unroll
        for (int o = 0; o < 128; ++o) a = fmaf(L0[o], n2_w[o * 64 + c], a);
        M0[c] = a + n2_b[c];
      } else {
        #pragma unroll
        for (int o = 0; o < 128; ++o) a = fmaf(L1[o], n2_w[o * 64 + c], a);
        M1[c] = a;
      } }
    __syncthreads();
    // Phase E: L0 = ce = c3@E1r ; L1 = ne = (un + 128*c3)@E1s
    { int g = t >> 7, o = t & 127;
      float a = 0.f;
      if (g == 0) {
        #pragma unroll
        for (int k = 0; k < 64; ++k) a = fmaf(M0[k], e1_w[k * 128 + o], a);
        L0[o] = a;
      } else {
        #pragma unroll
        for (int k = 0; k < 64; ++k) {
          float nb = fmaf(128.f, M0[k], M1[k]);
          a = fmaf(nb, e1_w[(64 + k) * 128 + o], a);
        }
        L1[o] = a;
      } }
    __syncthreads();
    // Phase F: M0 = g3 = (2*ce + ne/64 + 2*e1_b)@e2_w + 2*e2_b
    if (t < 64) { float a = 0.f;
      #pragma unroll
      for (int o = 0; o < 128; ++o) {
        float gv = fmaf(L1[o], (1.f / 64.f), fmaf(2.f, L0[o], 2.f * e1_b[o]));
        a = fmaf(gv, e2_w[o * 64 + t], a);
      }
      M0[t] = a + 2.f * e2_b[t]; }
    __syncthreads();
    // Phase G: h3 = g3@f1_w + f1_b
    if (t < 128) { float a = 0.f;
      #pragma unroll
      for (int k = 0; k < 64; ++k) a = fmaf(M0[k], f1_w[k * 128 + t], a);
      ws[WS_H3 + b * 128 + t] = a + f1_b[t]; }
  }
}

// ---------------- K2: per-node fused MLP (LDS ~44 KB) ----------------
__global__ __launch_bounds__(256) void k_main(
    const float* __restrict__ h, const float* __restrict__ pos,
    const float* __restrict__ f2_w, const float* __restrict__ f2_b,
    const float* __restrict__ ws, float* __restrict__ out)
{
  __shared__ __align__(16) float lH1[64 * 128];  // [k][d]  32 KB
  __shared__ __align__(16) float lx[16 * 64];    // [n][k]
  __shared__ float lp[16 * 2];
  __shared__ __align__(16) float lh1[16 * 128];  // [n][k]
  int blk = blockIdx.x, t = threadIdx.x;
  int b = blk >> 3, j0 = (blk & 7) * 16;
  for (int i = t; i < 2048; i += 256) ((float4*)lH1)[i] = ((const float4*)(ws + WS_H1))[i];
  ((float4*)lx)[t] = ((const float4*)(h + (size_t)(b * 128 + j0) * 64))[t];
  if (t < 32) lp[t] = pos[(b * 128 + j0) * 2 + t];
  __syncthreads();
  // h1 = relu(x@H1 + p@H2 + h3)   (H2/h3 broadcast reads straight from L1/L2)
  {
    int d = t & 127, g = t >> 7, n0 = g * 8;
    float h3v = ws[WS_H3 + b * 128 + d];
    float h2a = ws[WS_H2 + d], h2b = ws[WS_H2 + 128 + d];
    float acc[8];
    #pragma unroll
    for (int i = 0; i < 8; ++i)
      acc[i] = h3v + lp[(n0 + i) * 2] * h2a + lp[(n0 + i) * 2 + 1] * h2b;
    #pragma unroll 4
    for (int k = 0; k < 64; k += 4) {
      float h0 = lH1[k * 128 + d], h1v = lH1[(k + 1) * 128 + d],
            h2v = lH1[(k + 2) * 128 + d], h3w = lH1[(k + 3) * 128 + d];
      #pragma unroll
      for (int i = 0; i < 8; ++i) {
        float4 xv = *(const float4*)&lx[(n0 + i) * 64 + k];
        acc[i] = fmaf(xv.x, h0, fmaf(xv.y, h1v, fmaf(xv.z, h2v, fmaf(xv.w, h3w, acc[i]))));
      }
    }
    #pragma unroll
    for (int i = 0; i < 8; ++i) lh1[(n0 + i) * 128 + d] = fmaxf(acc[i], 0.f);
  }
  __syncthreads();
  // out = relu(h1@f2_w + f2_b); f2_w/f2_b read from global (L2-resident)
  {
    int d = t & 63, g = t >> 6, n0 = g * 4;
    float acc[4];
    float bias = f2_b[d];
    #pragma unroll
    for (int i = 0; i < 4; ++i) acc[i] = bias;
    #pragma unroll 4
    for (int k = 0; k < 128; k += 4) {
      float f0 = f2_w[k * 64 + d], f1v = f2_w[(k + 1) * 64 + d],
            f2v = f2_w[(k + 2) * 64 + d], f3v = f2_w[(k + 3) * 64 + d];
      #pragma unroll
      for (int i = 0; i < 4; ++i) {
        float4 hv = *(const float4*)&lh1[(n0 + i) * 128 + k];
        acc[i] = fmaf(hv.x, f0, fmaf(hv.y, f1v, fmaf(hv.z, f2v, fmaf(hv.w, f3v, acc[i]))));
      }
    }
    #pragma unroll
    for (int i = 0; i < 4; ++i)
      out[(size_t)(b * 128 + j0 + n0 + i) * 64 + d] = fmaxf(acc[i], 0.f);
  }
}

extern "C" void kernel_launch(void* const* d_in, const int* in_sizes, int n_in,
                              void* d_out, int out_size, void* d_ws, size_t ws_size,
                              hipStream_t stream) {
  const float* h    = (const float*)d_in[0];
  const float* pos  = (const float*)d_in[1];
  const float* se_w = (const float*)d_in[2];
  const float* se_b = (const float*)d_in[3];
  const float* s1_w = (const float*)d_in[4];
  const float* s1_b = (const float*)d_in[5];
  const float* s2_w = (const float*)d_in[6];
  const float* s2_b = (const float*)d_in[7];
  const float* n1_w = (const float*)d_in[8];
  const float* n1_b = (const float*)d_in[9];
  const float* n2_w = (const float*)d_in[10];
  const float* n2_b = (const float*)d_in[11];
  const float* e1_w = (const float*)d_in[12];
  const float* e1_b = (const float*)d_in[13];
  const float* e2_w = (const float*)d_in[14];
  const float* e2_b = (const float*)d_in[15];
  const float* f1_w = (const float*)d_in[16];
  const float* f1_b = (const float*)d_in[17];
  const float* f2_w = (const float*)d_in[18];
  const float* f2_b = (const float*)d_in[19];
  float* ws = (float*)d_ws;
  float* out = (float*)d_out;

  hipLaunchKernelGGL(k_prep, dim3(64), dim3(256), 0, stream,
                     h, pos, se_w, se_b, s1_w, s1_b, s2_w, s2_b,
                     n1_w, n1_b, n2_w, n2_b, e1_w, e1_b, e2_w, e2_b,
                     f1_w, f1_b, ws);
  hipLaunchKernelGGL(k_main, dim3(256), dim3(256), 0, stream, h, pos, f2_w, f2_b, ws, out);
}